// Round 2
// baseline (91.411 us; speedup 1.0000x reference)
//
#include <hip/hip_runtime.h>
#include <stdint.h>

// IndexedLinearLayer as implicit-A GEMM:
//   out[b,o] = sum_{q,i} x[b,i]*[idx[b,i]==q] * T[q*1024+i, o] + bias[o]
// A = masked x (bf16, built in LDS), B = table chunk (fp32 -> bf16 on the fly),
// MFMA 16x16x32_bf16, split-K over quantiles with fp32 atomicAdd reduce.
//
// Tiles: M=32 (batch), N=128 (outs), K-chunk=1024 (one quantile).
// Grid = 16 bt * 2 nh * 16 q = 512 blocks (2/CU), 256 threads (4 waves).
// blockIdx = (bt*2+nh)*16 + q  ->  XCD = q%8: all 32 same-q blocks share one
// XCD's L2, so each 1 MB table chunk is L2-resident (L3->L2 ~ table once).

constexpr int SIZE_IN  = 1024;
constexpr int SIZE_OUT = 256;
constexpr int TM = 32;             // batch tile
constexpr int TN = 128;            // out tile
constexpr int A_STRIDE = 1032;     // bf16 elems/row, +8 pad (16B) -> conflict-free b128

typedef short short8   __attribute__((ext_vector_type(8)));
typedef float floatx4  __attribute__((ext_vector_type(4)));

// pack two fp32 -> two bf16 (round-half-up) in one dword via v_perm
__device__ inline uint32_t pack2bf(float lo, float hi) {
    uint32_t a = __float_as_uint(lo) + 0x8000u;
    uint32_t b = __float_as_uint(hi) + 0x8000u;
    return __builtin_amdgcn_perm(b, a, 0x07060302);  // {b.hi16, a.hi16}
}

__global__ __launch_bounds__(256, 2)
void idxlin_mfma(const float* __restrict__ x,      // [512,1024]
                 const int*   __restrict__ idx,    // [512,1024]
                 const float* __restrict__ table,  // [16*1024, 256]
                 const float* __restrict__ bias,   // [256]
                 float*       __restrict__ out)    // [512,256], pre-zeroed
{
    __shared__ uint16_t Alds[TM * A_STRIDE];       // 66 KB

    const int tid = threadIdx.x;
    const int q   = blockIdx.x & 15;
    const int r   = blockIdx.x >> 4;
    const int nh  = r & 1;
    const int bt  = r >> 1;
    const int b0  = bt * TM;
    const int n0  = nh * TN;

    // ---- Stage masked-x A-tile into LDS (bf16). Iter s fills row m=s. ----
    const float4* x4 = reinterpret_cast<const float4*>(x   + b0 * SIZE_IN);
    const int4*   i4 = reinterpret_cast<const int4*>(idx + b0 * SIZE_IN);
    #pragma unroll 4
    for (int s = 0; s < TM; ++s) {
        const int f = s * 256 + tid;               // f>>8 == s, f&255 == tid
        const float4 xv = x4[f];
        const int4   iv = i4[f];
        const float v0 = (iv.x == q) ? xv.x : 0.f;
        const float v1 = (iv.y == q) ? xv.y : 0.f;
        const float v2 = (iv.z == q) ? xv.z : 0.f;
        const float v3 = (iv.w == q) ? xv.w : 0.f;
        uint2 d;
        d.x = pack2bf(v0, v1);
        d.y = pack2bf(v2, v3);
        *reinterpret_cast<uint2*>(&Alds[s * A_STRIDE + tid * 4]) = d;
    }
    __syncthreads();

    // ---- MFMA K-loop ----
    const int lane  = tid & 63;
    const int w     = tid >> 6;        // wave: owns out cols [n0+w*32, +32)
    const int nlane = lane & 15;
    const int quad  = lane >> 4;

    // B element: table[(q*1024 + kb*32 + quad*8 + j)*256 + n0 + w*32 + nt*16 + nlane]
    const float* bp = table + (q * SIZE_IN + quad * 8) * SIZE_OUT + n0 + w * 32 + nlane;
    const uint16_t* arow0 = &Alds[(0 * 16 + nlane) * A_STRIDE + quad * 8];
    const uint16_t* arow1 = &Alds[(1 * 16 + nlane) * A_STRIDE + quad * 8];

    floatx4 acc[2][2] = {{{0.f,0.f,0.f,0.f},{0.f,0.f,0.f,0.f}},
                         {{0.f,0.f,0.f,0.f},{0.f,0.f,0.f,0.f}}};

    #pragma unroll 2
    for (int kb = 0; kb < SIZE_IN / 32; ++kb) {
        float wv[2][8];
        #pragma unroll
        for (int nt = 0; nt < 2; ++nt)
            #pragma unroll
            for (int j = 0; j < 8; ++j)
                wv[nt][j] = bp[j * SIZE_OUT + nt * 16];   // imm offsets, coalesced 64B

        const short8 a0 = *reinterpret_cast<const short8*>(arow0 + kb * 32);
        const short8 a1 = *reinterpret_cast<const short8*>(arow1 + kb * 32);

        #pragma unroll
        for (int nt = 0; nt < 2; ++nt) {
            union { uint32_t u[4]; short8 s; } bf;
            bf.u[0] = pack2bf(wv[nt][0], wv[nt][1]);
            bf.u[1] = pack2bf(wv[nt][2], wv[nt][3]);
            bf.u[2] = pack2bf(wv[nt][4], wv[nt][5]);
            bf.u[3] = pack2bf(wv[nt][6], wv[nt][7]);
            acc[0][nt] = __builtin_amdgcn_mfma_f32_16x16x32_bf16(a0, bf.s, acc[0][nt], 0, 0, 0);
            acc[1][nt] = __builtin_amdgcn_mfma_f32_16x16x32_bf16(a1, bf.s, acc[1][nt], 0, 0, 0);
        }
        bp += 32 * SIZE_OUT;
    }

    // ---- Split-K reduce: atomicAdd into pre-zeroed out ----
    // C/D layout: col = lane&15, row = quad*4 + reg   [m89/m91]
    #pragma unroll
    for (int mt = 0; mt < 2; ++mt)
        #pragma unroll
        for (int nt = 0; nt < 2; ++nt)
            #pragma unroll
            for (int rr = 0; rr < 4; ++rr) {
                const int bg = b0 + mt * 16 + quad * 4 + rr;
                const int o  = n0 + w * 32 + nt * 16 + nlane;
                atomicAdd(&out[bg * SIZE_OUT + o], acc[mt][nt][rr]);
            }

    // ---- Bias: added once per (b,o) by the q==0 block of each tile ----
    if (q == 0) {
        const int o_l = tid & (TN - 1);
        const int m0  = (tid >> 7) * 16;
        const float bv = bias[n0 + o_l];
        #pragma unroll
        for (int rr = 0; rr < 16; ++rr)
            atomicAdd(&out[(b0 + m0 + rr) * SIZE_OUT + n0 + o_l], bv);
    }
}

extern "C" void kernel_launch(void* const* d_in, const int* in_sizes, int n_in,
                              void* d_out, int out_size, void* d_ws, size_t ws_size,
                              hipStream_t stream) {
    const float* x     = (const float*)d_in[0];
    const int*   idx   = (const int*)d_in[1];
    const float* table = (const float*)d_in[2];
    const float* bias  = (const float*)d_in[3];
    float*       out   = (float*)d_out;

    hipMemsetAsync(out, 0, (size_t)out_size * sizeof(float), stream);
    idxlin_mfma<<<dim3(512), dim3(256), 0, stream>>>(x, idx, table, bias, out);
}

// Round 3
// 89.598 us; speedup vs baseline: 1.0202x; 1.0202x over previous
//
#include <hip/hip_runtime.h>
#include <stdint.h>

// IndexedLinearLayer as implicit-A GEMM:
//   out[b,o] = sum_{q,i} x[b,i]*[idx[b,i]==q] * T[q*1024+i, o] + bias[o]
// A = masked x (bf16, built in LDS), B = table chunk (fp32 -> bf16 on the fly),
// MFMA 16x16x32_bf16, split-K over quantiles.
//
// R3 change vs R2: split-K reduction via d_ws partials + reduce kernel
// (plain coalesced stores) instead of 2.1M cross-XCD atomicAdds, which
// serialized at the memory-side cache and ate ~70us (rocprof showed the
// dispatch at 30ms under serialized replay, VALUBusy 1.5%).
//
// Tiles: M=32 (batch), N=128 (outs), K-chunk=1024 (one quantile).
// Grid = 16 bt * 2 nh * 16 q = 512 blocks (2/CU), 256 threads (4 waves).
// blockIdx = r*16 + q -> XCD = q%8: all 32 same-q blocks share one XCD's L2,
// so each 1 MB table chunk is L2-resident after first touch.

constexpr int SIZE_IN  = 1024;
constexpr int SIZE_OUT = 256;
constexpr int BATCH    = 512;
constexpr int TM = 32;             // batch tile
constexpr int TN = 128;            // out tile
constexpr int A_STRIDE = 1032;     // bf16 elems/row, +8 pad -> 2-way-max (free) b128

constexpr size_t WS_NEED = (size_t)16 * BATCH * SIZE_OUT * sizeof(float); // 8 MB

typedef short short8   __attribute__((ext_vector_type(8)));
typedef float floatx4  __attribute__((ext_vector_type(4)));

// pack two fp32 -> two bf16 (round-half-up) in one dword via v_perm
__device__ inline uint32_t pack2bf(float lo, float hi) {
    uint32_t a = __float_as_uint(lo) + 0x8000u;
    uint32_t b = __float_as_uint(hi) + 0x8000u;
    return __builtin_amdgcn_perm(b, a, 0x07060302);  // {b.hi16, a.hi16}
}

template <bool USE_WS>
__global__ __launch_bounds__(256, 2)
void idxlin_mfma(const float* __restrict__ x,      // [512,1024]
                 const int*   __restrict__ idx,    // [512,1024]
                 const float* __restrict__ table,  // [16*1024, 256]
                 const float* __restrict__ bias,   // [256]
                 float*       __restrict__ out,    // [512,256] (atomic path: pre-zeroed)
                 float*       __restrict__ ws)     // [16,512,256] partials (ws path)
{
    __shared__ uint16_t Alds[TM * A_STRIDE];       // 66 KB -> 2 blocks/CU

    const int tid = threadIdx.x;
    const int q   = blockIdx.x & 15;
    const int r   = blockIdx.x >> 4;
    const int nh  = r & 1;
    const int bt  = r >> 1;
    const int b0  = bt * TM;
    const int n0  = nh * TN;

    // ---- Stage masked-x A-tile into LDS (bf16). Iter s fills row m=s. ----
    const float4* x4 = reinterpret_cast<const float4*>(x   + b0 * SIZE_IN);
    const int4*   i4 = reinterpret_cast<const int4*>(idx + b0 * SIZE_IN);
    #pragma unroll 4
    for (int s = 0; s < TM; ++s) {
        const int f = s * 256 + tid;               // row s, float4-col tid
        const float4 xv = x4[f];
        const int4   iv = i4[f];
        const float v0 = (iv.x == q) ? xv.x : 0.f;
        const float v1 = (iv.y == q) ? xv.y : 0.f;
        const float v2 = (iv.z == q) ? xv.z : 0.f;
        const float v3 = (iv.w == q) ? xv.w : 0.f;
        uint2 d;
        d.x = pack2bf(v0, v1);
        d.y = pack2bf(v2, v3);
        *reinterpret_cast<uint2*>(&Alds[s * A_STRIDE + tid * 4]) = d;
    }
    __syncthreads();

    // ---- MFMA K-loop ----
    const int lane  = tid & 63;
    const int w     = tid >> 6;        // wave: owns out cols [n0+w*32, +32)
    const int nlane = lane & 15;
    const int quad  = lane >> 4;

    const float* bp = table + (q * SIZE_IN + quad * 8) * SIZE_OUT + n0 + w * 32 + nlane;
    const uint16_t* arow0 = &Alds[(0 * 16 + nlane) * A_STRIDE + quad * 8];
    const uint16_t* arow1 = &Alds[(1 * 16 + nlane) * A_STRIDE + quad * 8];

    floatx4 acc[2][2] = {{{0.f,0.f,0.f,0.f},{0.f,0.f,0.f,0.f}},
                         {{0.f,0.f,0.f,0.f},{0.f,0.f,0.f,0.f}}};

    #pragma unroll 2
    for (int kb = 0; kb < SIZE_IN / 32; ++kb) {
        float wv[2][8];
        #pragma unroll
        for (int nt = 0; nt < 2; ++nt)
            #pragma unroll
            for (int j = 0; j < 8; ++j)
                wv[nt][j] = bp[j * SIZE_OUT + nt * 16];   // imm offsets, 64B/quad coalesced

        const short8 a0 = *reinterpret_cast<const short8*>(arow0 + kb * 32);
        const short8 a1 = *reinterpret_cast<const short8*>(arow1 + kb * 32);

        #pragma unroll
        for (int nt = 0; nt < 2; ++nt) {
            union { uint32_t u[4]; short8 s; } bf;
            bf.u[0] = pack2bf(wv[nt][0], wv[nt][1]);
            bf.u[1] = pack2bf(wv[nt][2], wv[nt][3]);
            bf.u[2] = pack2bf(wv[nt][4], wv[nt][5]);
            bf.u[3] = pack2bf(wv[nt][6], wv[nt][7]);
            acc[0][nt] = __builtin_amdgcn_mfma_f32_16x16x32_bf16(a0, bf.s, acc[0][nt], 0, 0, 0);
            acc[1][nt] = __builtin_amdgcn_mfma_f32_16x16x32_bf16(a1, bf.s, acc[1][nt], 0, 0, 0);
        }
        bp += 32 * SIZE_OUT;
    }

    // ---- Split-K output. C/D layout: col = lane&15, row = quad*4 + reg ----
    if (USE_WS) {
        float* wsq = ws + ((size_t)(q * BATCH + b0)) * SIZE_OUT + n0;
        #pragma unroll
        for (int mt = 0; mt < 2; ++mt)
            #pragma unroll
            for (int nt = 0; nt < 2; ++nt)
                #pragma unroll
                for (int rr = 0; rr < 4; ++rr) {
                    const int row = mt * 16 + quad * 4 + rr;
                    const int col = w * 32 + nt * 16 + nlane;
                    wsq[row * SIZE_OUT + col] = acc[mt][nt][rr];
                }
    } else {
        #pragma unroll
        for (int mt = 0; mt < 2; ++mt)
            #pragma unroll
            for (int nt = 0; nt < 2; ++nt)
                #pragma unroll
                for (int rr = 0; rr < 4; ++rr) {
                    const int bg = b0 + mt * 16 + quad * 4 + rr;
                    const int o  = n0 + w * 32 + nt * 16 + nlane;
                    atomicAdd(&out[bg * SIZE_OUT + o], acc[mt][nt][rr]);
                }
        if (q == 0) {
            const int o_l = tid & (TN - 1);
            const int m0  = (tid >> 7) * 16;
            const float bv = bias[n0 + o_l];
            #pragma unroll
            for (int rr = 0; rr < 16; ++rr)
                atomicAdd(&out[(b0 + m0 + rr) * SIZE_OUT + n0 + o_l], bv);
        }
    }
}

// Sum 16 q-partials + bias. Flat float4 index e over [512 b][64 o4].
__global__ __launch_bounds__(256)
void reduce_ws(const float* __restrict__ ws, const float* __restrict__ bias,
               float* __restrict__ out)
{
    const int e  = blockIdx.x * 256 + threadIdx.x;      // 0..32767
    const int o4 = e & 63;
    const float4* w4 = reinterpret_cast<const float4*>(ws);
    float4 s = reinterpret_cast<const float4*>(bias)[o4];
    #pragma unroll
    for (int q = 0; q < 16; ++q) {
        const float4 v = w4[(size_t)q * (BATCH * SIZE_OUT / 4) + e];
        s.x += v.x; s.y += v.y; s.z += v.z; s.w += v.w;
    }
    reinterpret_cast<float4*>(out)[e] = s;
}

extern "C" void kernel_launch(void* const* d_in, const int* in_sizes, int n_in,
                              void* d_out, int out_size, void* d_ws, size_t ws_size,
                              hipStream_t stream) {
    const float* x     = (const float*)d_in[0];
    const int*   idx   = (const int*)d_in[1];
    const float* table = (const float*)d_in[2];
    const float* bias  = (const float*)d_in[3];
    float*       out   = (float*)d_out;
    float*       ws    = (float*)d_ws;

    if (ws_size >= WS_NEED) {
        idxlin_mfma<true><<<dim3(512), dim3(256), 0, stream>>>(x, idx, table, bias, out, ws);
        reduce_ws<<<dim3(BATCH * SIZE_OUT / 4 / 256), dim3(256), 0, stream>>>(ws, bias, out);
    } else {
        hipMemsetAsync(out, 0, (size_t)out_size * sizeof(float), stream);
        idxlin_mfma<false><<<dim3(512), dim3(256), 0, stream>>>(x, idx, table, bias, out, ws);
    }
}